// Round 4
// baseline (130.777 us; speedup 1.0000x reference)
//
#include <hip/hip_runtime.h>
#include <hip/hip_bf16.h>

#define NN 4096
#define FD 128
#define NDIM 2
#define CAP 256

// ---------- workspace layout (float offsets) ----------
// hmat [2][3][4096][128] fp32 : q=0 X@Ws (h_s), q=1 X@Wu, q=2 X@Wd
// svec [2][4][4096]           : v=0 s1u, 1 s2u, 2 s1d, 3 s2d
// hp   [2][4][4096][128] fp32 : split-K partials of L@h0
// gu,gd [2][4096][128]
// h0T  [2][128][4096] f16     : (X@Wp) transposed, f16 (B operand of L-GEMM)
#define OFF_HMAT 0
#define OFF_SVEC 3145728
#define OFF_HP   3178496
#define OFF_GU   7372800
#define OFF_GD   8421376
#define OFF_H0T  9469952

typedef _Float16 f16x8 __attribute__((ext_vector_type(8)));
typedef float f32x4 __attribute__((ext_vector_type(4)));

union P4 { _Float16 h[4]; int2 i2; };

__device__ __forceinline__ float f4get(const float4& v, int j) {
    return j == 0 ? v.x : j == 1 ? v.y : j == 2 ? v.z : v.w;
}

// ---------------- K1: MFMA f16 GEMM  h = X @ W_p, tile 128x128, K=128 ----------------
__global__ __launch_bounds__(256) void k_xw(
    const float* __restrict__ X, const float* __restrict__ Wp,
    const float* __restrict__ Wsm, const float* __restrict__ Wu,
    const float* __restrict__ Wd, float* __restrict__ hmat,
    _Float16* __restrict__ h0T) {
  int d = blockIdx.z, p = blockIdx.y;
  int r0 = blockIdx.x * 128;
  const float* W = (p == 0 ? Wp : p == 1 ? Wsm : p == 2 ? Wu : Wd) + (size_t)d * FD * FD;
  const float* Xd = X + ((size_t)d * NN + r0) * FD;
  __shared__ int4 As4[2048];  // 32 KB: A[128 rows][128 k] f16, XOR-swizzled
  __shared__ int4 Bs4[2048];  // 32 KB: Bt[128 n][128 k] f16, XOR-swizzled
  char* As = (char*)As4; char* Bs = (char*)Bs4;
  int t = threadIdx.x;

#pragma unroll 4
  for (int u = 0; u < 16; u++) {
    int id = t + u * 256;
    int row = id >> 5, k4 = (id & 31) * 4;
    float4 v = *(const float4*)(Xd + (size_t)row * FD + k4);
    P4 pk;
    pk.h[0] = (_Float16)v.x; pk.h[1] = (_Float16)v.y;
    pk.h[2] = (_Float16)v.z; pk.h[3] = (_Float16)v.w;
    int off = (row * 256 + k4 * 2) ^ ((row & 7) << 4);
    *(int2*)(As + off) = pk.i2;
  }
#pragma unroll 4
  for (int u = 0; u < 16; u++) {
    int id = t + u * 256;
    int k = id >> 5, n4 = (id & 31) * 4;
    float4 v = *(const float4*)(W + (size_t)k * FD + n4);
#pragma unroll
    for (int j = 0; j < 4; j++) {
      int n = n4 + j;
      int off = (n * 256 + k * 2) ^ ((n & 7) << 4);
      *(_Float16*)(Bs + off) = (_Float16)f4get(v, j);
    }
  }
  __syncthreads();

  int w = t >> 6, l = t & 63;
  int lr = l & 15, lkb = (l >> 4) * 16;
  f32x4 acc[2][8] = {};
#pragma unroll
  for (int kb = 0; kb < 4; kb++) {
    f16x8 a[2], b[8];
#pragma unroll
    for (int m = 0; m < 2; m++) {
      int row = w * 32 + m * 16 + lr;
      int off = (row * 256 + kb * 64 + lkb) ^ ((row & 7) << 4);
      a[m] = *(const f16x8*)(As + off);
    }
#pragma unroll
    for (int n = 0; n < 8; n++) {
      int rn = n * 16 + lr;
      int off = (rn * 256 + kb * 64 + lkb) ^ ((rn & 7) << 4);
      b[n] = *(const f16x8*)(Bs + off);
    }
#pragma unroll
    for (int m = 0; m < 2; m++)
#pragma unroll
      for (int n = 0; n < 8; n++)
        acc[m][n] = __builtin_amdgcn_mfma_f32_16x16x32_f16(a[m], b[n], acc[m][n], 0, 0, 0);
  }

  if (p == 0) {
    _Float16* hT = h0T + (size_t)d * FD * NN;
#pragma unroll
    for (int m = 0; m < 2; m++)
#pragma unroll
      for (int n = 0; n < 8; n++) {
        int col = n * 16 + lr;
        int grow = r0 + w * 32 + m * 16 + (l >> 4) * 4;
        P4 pk;
#pragma unroll
        for (int r = 0; r < 4; r++) pk.h[r] = (_Float16)acc[m][n][r];
        *(int2*)(hT + (size_t)col * NN + grow) = pk.i2;
      }
  } else {
    float* o = hmat + ((size_t)(d * 3 + p - 1) * NN + r0) * FD;
#pragma unroll
    for (int m = 0; m < 2; m++)
#pragma unroll
      for (int n = 0; n < 8; n++)
#pragma unroll
        for (int r = 0; r < 4; r++)
          o[(size_t)(w * 32 + m * 16 + (l >> 4) * 4 + r) * FD + n * 16 + lr] = acc[m][n][r];
  }
}

// ---------------- K1b: svec = h @ a ----------------
__global__ __launch_bounds__(256) void k_svec(
    const float* __restrict__ hmat, const float* __restrict__ au1,
    const float* __restrict__ au2, const float* __restrict__ ad1,
    const float* __restrict__ ad2, float* __restrict__ svec) {
  int v = blockIdx.y, d = blockIdx.z;
  int w = threadIdx.x >> 6, lane = threadIdx.x & 63;
  int i = blockIdx.x * 4 + w;
  const float* a = (v == 0 ? au1 : v == 1 ? au2 : v == 2 ? ad1 : ad2) + (size_t)d * FD;
  const float* h = hmat + ((size_t)(d * 3 + 1 + (v >> 1)) * NN + i) * FD;
  float x = h[lane] * a[lane] + h[64 + lane] * a[64 + lane];
#pragma unroll
  for (int o = 1; o < 64; o <<= 1) x += __shfl_xor(x, o);
  if (lane == 0) svec[(size_t)(d * 4 + v) * NN + i] = x;
}

// ---------------- K2: MFMA f16 GEMM  hp[d][ks] = L[d][:,slice] @ h0[slice,:]
//                  BM=64, 512 blocks = 2 blocks/CU for stage/MFMA overlap ----
__global__ __launch_bounds__(256) void k_lgemm(
    const float* __restrict__ L, const _Float16* __restrict__ h0T,
    float* __restrict__ hp) {
  int d = blockIdx.z, ks = blockIdx.y;
  int r0 = blockIdx.x * 64;
  const float* Lr = L + (size_t)d * NN * NN;
  const _Float16* hT = h0T + (size_t)d * FD * NN;
  __shared__ int4 As4[512];   //  8 KB: A[64 rows][64 k] f16, XOR-swizzled
  __shared__ int4 Bs4[1024];  // 16 KB: Bt[128 n][64 k] f16, XOR-swizzled
  char* As = (char*)As4; char* Bs = (char*)Bs4;
  int t = threadIdx.x;
  int w = t >> 6, l = t & 63;
  int lr = l & 15, lkb = (l >> 4) * 16;
  f32x4 acc[8] = {};
  int kbeg = ks * 1024;
  for (int kk = kbeg; kk < kbeg + 1024; kk += 64) {
#pragma unroll
    for (int u = 0; u < 4; u++) {
      int id = t + u * 256;
      int row = id >> 4, k4 = (id & 15) * 4;
      float4 v = *(const float4*)(Lr + (size_t)(r0 + row) * NN + kk + k4);
      P4 pk;
      pk.h[0] = (_Float16)v.x; pk.h[1] = (_Float16)v.y;
      pk.h[2] = (_Float16)v.z; pk.h[3] = (_Float16)v.w;
      int off = (row * 128 + k4 * 2) ^ ((row & 7) << 4);
      *(int2*)(As + off) = pk.i2;
    }
#pragma unroll
    for (int u = 0; u < 4; u++) {
      int id = t + u * 256;
      int n = id >> 3, k8 = (id & 7) * 8;
      int4 v = *(const int4*)(hT + (size_t)n * NN + kk + k8);
      int off = (n * 128 + k8 * 2) ^ ((n & 7) << 4);
      *(int4*)(Bs + off) = v;
    }
    __syncthreads();
#pragma unroll
    for (int kb = 0; kb < 2; kb++) {
      int row = w * 16 + lr;
      int offA = (row * 128 + kb * 64 + lkb) ^ ((row & 7) << 4);
      f16x8 a = *(const f16x8*)(As + offA);
      f16x8 b[8];
#pragma unroll
      for (int n = 0; n < 8; n++) {
        int rn = n * 16 + lr;
        int off = (rn * 128 + kb * 64 + lkb) ^ ((rn & 7) << 4);
        b[n] = *(const f16x8*)(Bs + off);
      }
#pragma unroll
      for (int n = 0; n < 8; n++)
        acc[n] = __builtin_amdgcn_mfma_f32_16x16x32_f16(a, b[n], acc[n], 0, 0, 0);
    }
    __syncthreads();
  }
  float* o = hp + ((size_t)(d * 4 + ks) * NN + r0) * FD;
#pragma unroll
  for (int n = 0; n < 8; n++)
#pragma unroll
    for (int r = 0; r < 4; r++)
      o[(size_t)(w * 16 + (l >> 4) * 4 + r) * FD + n * 16 + lr] = acc[n][r];
}

// ---------------- K3: GAT, block-per-row (4 waves cooperate on one row) ----
#define BAL(val, idxexpr)                                          \
  {                                                                \
    unsigned long long m = __ballot((val) == 1.0f);                \
    if (m) {                                                       \
      if ((val) == 1.0f) {                                         \
        int pos = c + __popcll(m & ((1ull << lane) - 1ull));       \
        if (pos < 64) ejt[w][pos] = (idxexpr);                     \
      }                                                            \
      c += __popcll(m);                                            \
    }                                                              \
  }

__global__ __launch_bounds__(256) void k_gat(
    const float* __restrict__ Lu, const float* __restrict__ Ldn,
    const float* __restrict__ hmat, const float* __restrict__ svec,
    float* __restrict__ gu, float* __restrict__ gd) {
  int i = blockIdx.x;
  int a = blockIdx.y, d = blockIdx.z;
  const float* Arow = (a ? Ldn : Lu) + ((size_t)d * NN + i) * (size_t)NN;
  const float* h = hmat + (size_t)(d * 3 + 1 + a) * NN * FD;
  const float* s1 = svec + (size_t)(d * 4 + 2 * a) * NN;
  const float* s2 = svec + (size_t)(d * 4 + 2 * a + 1) * NN;
  float* g = (a ? gd : gu) + ((size_t)d * NN + i) * FD;

  __shared__ int ejt[4][64];
  __shared__ int wcnt[4];
  __shared__ int ejs[CAP];
  __shared__ float wts[CAP];
  __shared__ float red[256];
  __shared__ float invs;

  int t = threadIdx.x, w = t >> 6, lane = t & 63;

  // --- scan: whole 16 KB row in flight at once (4 float4 per thread) ---
  int bi = t * 16;
  float4 v0 = *(const float4*)(Arow + bi);
  float4 v1 = *(const float4*)(Arow + bi + 4);
  float4 v2 = *(const float4*)(Arow + bi + 8);
  float4 v3 = *(const float4*)(Arow + bi + 12);
  int c = 0;
  BAL(v0.x, bi + 0)  BAL(v0.y, bi + 1)  BAL(v0.z, bi + 2)  BAL(v0.w, bi + 3)
  BAL(v1.x, bi + 4)  BAL(v1.y, bi + 5)  BAL(v1.z, bi + 6)  BAL(v1.w, bi + 7)
  BAL(v2.x, bi + 8)  BAL(v2.y, bi + 9)  BAL(v2.z, bi + 10) BAL(v2.w, bi + 11)
  BAL(v3.x, bi + 12) BAL(v3.y, bi + 13) BAL(v3.z, bi + 14) BAL(v3.w, bi + 15)
  if (lane == 0) wcnt[w] = min(c, 64);
  __syncthreads();

  // --- merge per-wave segments (prefix over 4 counts) ---
  int c0 = wcnt[0], c1 = wcnt[1], c2 = wcnt[2], c3 = wcnt[3];
  int base = (w > 0 ? c0 : 0) + (w > 1 ? c1 : 0) + (w > 2 ? c2 : 0);
  int cnt = c0 + c1 + c2 + c3;  // <= 256 by construction
  int myc = wcnt[w];
  if (lane < myc) ejs[base + lane] = ejt[w][lane];
  __syncthreads();

  // --- softmax over edges (wave 0, <=4 rounds of 64) ---
  if (w == 0) {
    float s1i = s1[i];
    float sc0 = -1e30f, sc1 = -1e30f, sc2 = -1e30f, sc3 = -1e30f;
    if (lane < cnt)       { float x = s1i + s2[ejs[lane]];       sc0 = x > 0.f ? x : 0.01f * x; }
    if (64 + lane < cnt)  { float x = s1i + s2[ejs[64 + lane]];  sc1 = x > 0.f ? x : 0.01f * x; }
    if (128 + lane < cnt) { float x = s1i + s2[ejs[128 + lane]]; sc2 = x > 0.f ? x : 0.01f * x; }
    if (192 + lane < cnt) { float x = s1i + s2[ejs[192 + lane]]; sc3 = x > 0.f ? x : 0.01f * x; }
    float mx = fmaxf(fmaxf(sc0, sc1), fmaxf(sc2, sc3));
#pragma unroll
    for (int o = 1; o < 64; o <<= 1) mx = fmaxf(mx, __shfl_xor(mx, o));
    float p0 = 0.f, p1 = 0.f, p2 = 0.f, p3 = 0.f;
    if (lane < cnt)       { p0 = expf(sc0 - mx); wts[lane] = p0; }
    if (64 + lane < cnt)  { p1 = expf(sc1 - mx); wts[64 + lane] = p1; }
    if (128 + lane < cnt) { p2 = expf(sc2 - mx); wts[128 + lane] = p2; }
    if (192 + lane < cnt) { p3 = expf(sc3 - mx); wts[192 + lane] = p3; }
    float sum = p0 + p1 + p2 + p3;
#pragma unroll
    for (int o = 1; o < 64; o <<= 1) sum += __shfl_xor(sum, o);
    if (lane == 0) invs = (cnt > 0) ? 1.0f / sum : 0.0f;
  }
  __syncthreads();

  // --- gather: thread t owns column t&127, edges stride-2 from t>>7 ---
  int col = t & 127;
  float acc = 0.0f;
  int e = t >> 7;
  for (; e + 6 < cnt; e += 8) {
    int j0 = ejs[e], j1 = ejs[e + 2], j2 = ejs[e + 4], j3 = ejs[e + 6];
    float w0 = wts[e], w1 = wts[e + 2], w2 = wts[e + 4], w3 = wts[e + 6];
    float h0 = h[(size_t)j0 * FD + col];
    float h1 = h[(size_t)j1 * FD + col];
    float h2 = h[(size_t)j2 * FD + col];
    float h3 = h[(size_t)j3 * FD + col];
    acc += w0 * h0 + w1 * h1 + w2 * h2 + w3 * h3;
  }
  for (; e < cnt; e += 2) acc += wts[e] * h[(size_t)ejs[e] * FD + col];
  red[t] = acc * invs;
  __syncthreads();
  if (t < 128) g[t] = red[t] + red[t + 128];
}

// ---------------- K4: combine with tanh ----------------
__global__ __launch_bounds__(256) void k_combine(
    const float* __restrict__ hmat, const float* __restrict__ hp,
    const float* __restrict__ gu, const float* __restrict__ gd,
    float* __restrict__ out) {
  const size_t tot4 = (size_t)NDIM * NN * FD / 4;
  for (size_t i4 = (size_t)blockIdx.x * blockDim.x + threadIdx.x; i4 < tot4;
       i4 += (size_t)gridDim.x * blockDim.x) {
    size_t i = i4 * 4;
    int d = (int)(i >> 19);
    size_t rem = i & 524287;
    float4 hs = *(const float4*)(hmat + ((size_t)(d * 3) << 19) + rem);
    float4 p0 = *(const float4*)(hp + ((size_t)(d * 4 + 0) << 19) + rem);
    float4 p1 = *(const float4*)(hp + ((size_t)(d * 4 + 1) << 19) + rem);
    float4 p2 = *(const float4*)(hp + ((size_t)(d * 4 + 2) << 19) + rem);
    float4 p3 = *(const float4*)(hp + ((size_t)(d * 4 + 3) << 19) + rem);
    float4 u = *(const float4*)(gu + ((size_t)d << 19) + rem);
    float4 dd = *(const float4*)(gd + ((size_t)d << 19) + rem);
    float4 o;
    o.x = tanhf(hs.x) + tanhf(u.x) + tanhf(dd.x) + tanhf(p0.x + p1.x + p2.x + p3.x);
    o.y = tanhf(hs.y) + tanhf(u.y) + tanhf(dd.y) + tanhf(p0.y + p1.y + p2.y + p3.y);
    o.z = tanhf(hs.z) + tanhf(u.z) + tanhf(dd.z) + tanhf(p0.z + p1.z + p2.z + p3.z);
    o.w = tanhf(hs.w) + tanhf(u.w) + tanhf(dd.w) + tanhf(p0.w + p1.w + p2.w + p3.w);
    *(float4*)(out + i) = o;
  }
}

extern "C" void kernel_launch(void* const* d_in, const int* in_sizes, int n_in,
                              void* d_out, int out_size, void* d_ws, size_t ws_size,
                              hipStream_t stream) {
  const float* X   = (const float*)d_in[0];
  const float* L   = (const float*)d_in[1];
  const float* Lu  = (const float*)d_in[2];
  const float* Ldn = (const float*)d_in[3];
  const float* Wp  = (const float*)d_in[4];
  const float* Wsm = (const float*)d_in[5];
  const float* Wu  = (const float*)d_in[6];
  const float* au1 = (const float*)d_in[7];
  const float* au2 = (const float*)d_in[8];
  const float* Wd  = (const float*)d_in[9];
  const float* ad1 = (const float*)d_in[10];
  const float* ad2 = (const float*)d_in[11];
  float* out = (float*)d_out;
  float* ws = (float*)d_ws;

  float* hmat = ws + OFF_HMAT;
  float* svec = ws + OFF_SVEC;
  float* hp   = ws + OFF_HP;
  float* gu   = ws + OFF_GU;
  float* gd   = ws + OFF_GD;
  _Float16* h0T = (_Float16*)(ws + OFF_H0T);

  k_xw<<<dim3(NN / 128, 4, NDIM), 256, 0, stream>>>(X, Wp, Wsm, Wu, Wd, hmat, h0T);
  k_svec<<<dim3(NN / 4, 4, NDIM), 256, 0, stream>>>(hmat, au1, au2, ad1, ad2, svec);
  k_lgemm<<<dim3(NN / 64, 4, NDIM), 256, 0, stream>>>(L, h0T, hp);
  k_gat<<<dim3(NN, 2, NDIM), 256, 0, stream>>>(Lu, Ldn, hmat, svec, gu, gd);
  k_combine<<<1024, 256, 0, stream>>>(hmat, hp, gu, gd, out);
}